// Round 10
// baseline (67.654 us; speedup 1.0000x reference)
//
#include <hip/hip_runtime.h>
#include <math.h>

// Model_78271484002488: B=8, L=512, D=32, N_PATCHES=16, N_REF=32, LAT=128, HM=4,
// FH=8, NL=3, FF=128, PRED=96.  All f32.

#define ISQ32 0.17677669529663687f   // 1/sqrt(32)
#define C128  (-0.07195578415606394f)  // -ln(1e4)/128
#define C32   (-0.28782313662425575f)  // -ln(1e4)/32

// ---------------------------------------------------------------------------
// K0: blocks [0,144): embed matvec, 32 rows/block (8 rows/wave).
//     blocks [144,656): obsBits via ballot.
__launch_bounds__(256)
__global__ void k_embed_mm(const float* __restrict__ x_mark,
                           const float* __restrict__ Wk,
                           const float* __restrict__ Wq,
                           const float* __restrict__ x_mask,
                           float* __restrict__ Kmat,
                           float* __restrict__ Qall,
                           unsigned* __restrict__ obsBits) {
    if (blockIdx.x >= 144) {
        const int gt = (blockIdx.x - 144) * 256 + threadIdx.x;
        const int w = gt >> 6, lane = gt & 63;
        const int bl = w * 2 + (lane >> 5);
        const int d = lane & 31;
        const unsigned long long mm = __ballot(x_mask[bl * 32 + d] > 0.0f);
        if (lane == 0)  obsBits[w * 2]     = (unsigned)(mm & 0xffffffffull);
        if (lane == 32) obsBits[w * 2 + 1] = (unsigned)(mm >> 32);
        return;
    }
    __shared__ float sTe[32][128];
    const int wv = threadIdx.x >> 6;
    const int lane = threadIdx.x & 63;
    const int bb = blockIdx.x;
    const int row0 = bb * 32 + wv * 8;
    const float dv = __expf((float)(2 * lane) * C128);
    #pragma unroll
    for (int rr = 0; rr < 8; ++rr) {
        const int row = row0 + rr;
        const float t = (row < 4096) ? x_mark[row] : (float)(row - 4096) * (512.0f / 511.0f);
        const float ang = t * dv;
        sTe[wv * 8 + rr][2 * lane]     = __sinf(ang);
        sTe[wv * 8 + rr][2 * lane + 1] = __cosf(ang);
    }
    __syncthreads();
    const float* W = (bb < 128) ? Wk : Wq;
    float a0[8], a1[8];
    #pragma unroll
    for (int rr = 0; rr < 8; ++rr) { a0[rr] = 0.f; a1[rr] = 0.f; }
    for (int k = 0; k < 128; ++k) {
        const float wa = W[k * 128 + lane];
        const float wb = W[k * 128 + lane + 64];
        #pragma unroll
        for (int rr = 0; rr < 8; ++rr) {
            const float te = sTe[wv * 8 + rr][k];
            a0[rr] = fmaf(te, wa, a0[rr]);
            a1[rr] = fmaf(te, wb, a1[rr]);
        }
    }
    #pragma unroll
    for (int rr = 0; rr < 8; ++rr) {
        const int row = row0 + rr;
        float* outp = (row < 4096) ? (Kmat + row * 128) : (Qall + (row - 4096) * 128);
        outp[lane] = a0[rr];
        outp[lane + 64] = a1[rr];
    }
}

// ---------------------------------------------------------------------------
// K1: fused patch attention, range-based.  block = (i,b,h); 256 threads.
__launch_bounds__(256)
__global__ void k_patch_attn(const float* __restrict__ x,
                             const float* __restrict__ x_mark,
                             const unsigned* __restrict__ obsBits,
                             const float* __restrict__ Kmat,
                             const float* __restrict__ Qall,
                             float* __restrict__ attn) {
    __shared__ float sQ[32][36];
    __shared__ float sK[96][36];
    __shared__ float sX[96][36];
    __shared__ float sS[32][100];
    __shared__ unsigned sBits[96];
    __shared__ int sLo, sHi;
    __shared__ unsigned sAV;
    const int tid = threadIdx.x;
    const int h = blockIdx.x & 3;
    const int b = (blockIdx.x >> 2) & 7;
    const int i = blockIdx.x >> 5;
    const float e0 = 32.0f * (float)i, e1 = 32.0f * (float)(i + 1);
    if (tid == 0) { sLo = 512; sHi = -1; sAV = 0u; }
    __syncthreads();
    #pragma unroll
    for (int k = 0; k < 4; ++k) {
        const int idx = tid + 256 * k;
        sQ[idx >> 5][idx & 31] = Qall[(i * 32 + (idx >> 5)) * 128 + h * 32 + (idx & 31)];
    }
    {
        int mylo = 512, myhi = -1;
        unsigned mybits = 0u;
        #pragma unroll
        for (int k = 0; k < 2; ++k) {
            const int l = tid + 256 * k;
            const float t = x_mark[b * 512 + l];
            if (t >= e0 && t <= e1) {
                mylo = min(mylo, l);
                myhi = max(myhi, l);
                mybits |= obsBits[b * 512 + l];
            }
        }
        #pragma unroll
        for (int off = 32; off > 0; off >>= 1) {
            mylo = min(mylo, __shfl_xor(mylo, off));
            myhi = max(myhi, __shfl_xor(myhi, off));
            mybits |= __shfl_xor(mybits, off);
        }
        if ((tid & 63) == 0) {
            atomicMin(&sLo, mylo);
            atomicMax(&sHi, myhi);
            atomicOr(&sAV, mybits);
        }
    }
    __syncthreads();
    const int lo = sLo, hi = sHi;
    const int NA = hi - lo + 1;
    const unsigned av = sAV;
    const int r = tid >> 3, dg = tid & 7;

    if (NA >= 1 && NA <= 96 && av == 0xffffffffu) {
        if (tid < NA) sBits[tid] = obsBits[b * 512 + lo + tid];
        for (int idx = tid; idx < NA * 32; idx += 256) {
            const int ll = idx >> 5, c = idx & 31;
            sK[ll][c] = Kmat[(b * 512 + lo + ll) * 128 + h * 32 + c];
            sX[ll][c] = x[(b * 512 + lo + ll) * 32 + c];
        }
        __syncthreads();
        float m = -1e30f;
        for (int ll = dg; ll < NA; ll += 8) {
            float p0 = 0.f, p1 = 0.f, p2 = 0.f, p3 = 0.f;
            #pragma unroll
            for (int e = 0; e < 32; e += 4) {
                p0 = fmaf(sQ[r][e],     sK[ll][e],     p0);
                p1 = fmaf(sQ[r][e + 1], sK[ll][e + 1], p1);
                p2 = fmaf(sQ[r][e + 2], sK[ll][e + 2], p2);
                p3 = fmaf(sQ[r][e + 3], sK[ll][e + 3], p3);
            }
            const float s = (p0 + p1 + p2 + p3) * ISQ32;
            sS[r][ll] = s;
            m = fmaxf(m, s);
        }
        #pragma unroll
        for (int off = 4; off > 0; off >>= 1) m = fmaxf(m, __shfl_xor(m, off));
        for (int ll = dg; ll < NA; ll += 8) sS[r][ll] = __expf(sS[r][ll] - m);
        __syncthreads();
        float num0 = 0.f, num1 = 0.f, num2 = 0.f, num3 = 0.f;
        float den0 = 0.f, den1 = 0.f, den2 = 0.f, den3 = 0.f;
        for (int ll = 0; ll < NA; ++ll) {
            const float e = sS[r][ll];
            const unsigned bits = sBits[ll];
            if ((bits >> dg) & 1u)        { den0 += e; num0 = fmaf(e, sX[ll][dg],      num0); }
            if ((bits >> (dg + 8)) & 1u)  { den1 += e; num1 = fmaf(e, sX[ll][dg + 8],  num1); }
            if ((bits >> (dg + 16)) & 1u) { den2 += e; num2 = fmaf(e, sX[ll][dg + 16], num2); }
            if ((bits >> (dg + 24)) & 1u) { den3 += e; num3 = fmaf(e, sX[ll][dg + 24], num3); }
        }
        float* ap = attn + ((i * 8 + b) * 32 + r) * 128 + h * 32;
        ap[dg]      = num0 / den0;
        ap[dg + 8]  = num1 / den1;
        ap[dg + 16] = num2 / den2;
        ap[dg + 24] = num3 / den3;
    } else {
        float m = -1e30f;
        float num[4] = {0.f, 0.f, 0.f, 0.f}, den[4] = {0.f, 0.f, 0.f, 0.f};
        for (int l = 0; l < 512; ++l) {
            const float t = x_mark[b * 512 + l];
            const unsigned bits = obsBits[b * 512 + l];
            const bool inr = (t >= e0 && t <= e1);
            const unsigned effD = (inr ? bits : 0u) | ~av;
            if (effD == 0u) continue;
            const unsigned effN = effD & bits;
            const float* Kp = Kmat + (b * 512 + l) * 128 + h * 32;
            float a = 0.f;
            #pragma unroll
            for (int e2 = 0; e2 < 32; ++e2) a = fmaf(sQ[r][e2], Kp[e2], a);
            const float s = a * ISQ32;
            float eNew;
            if (s > m) {
                const float scale = __expf(m - s);
                #pragma unroll
                for (int jj = 0; jj < 4; ++jj) { den[jj] *= scale; num[jj] *= scale; }
                m = s;
                eNew = 1.0f;
            } else {
                eNew = __expf(s - m);
            }
            const float* xp = x + (b * 512 + l) * 32;
            #pragma unroll
            for (int jj = 0; jj < 4; ++jj) {
                const int d = dg + 8 * jj;
                if ((effD >> d) & 1u) den[jj] += eNew;
                if ((effN >> d) & 1u) num[jj] = fmaf(eNew, xp[d], num[jj]);
            }
        }
        float* ap = attn + ((i * 8 + b) * 32 + r) * 128 + h * 32;
        #pragma unroll
        for (int jj = 0; jj < 4; ++jj) ap[dg + 8 * jj] = num[jj] / den[jj];
    }
}

// ---------------------------------------------------------------------------
// K2: reprs = attn(B,32,128) @ W_out + b_out;  z[(b*32+d)][i][r] = reprs + te16(i,r)
__global__ void k_reprs(const float* __restrict__ attn,
                        const float* __restrict__ W_out,
                        const float* __restrict__ b_out,
                        float* __restrict__ z) {
    __shared__ float sA[32][129];
    const int tid = threadIdx.x;
    const int b = blockIdx.x & 7;
    const int i = blockIdx.x >> 3;
    #pragma unroll
    for (int k = 0; k < 16; ++k) {
        const int idx = tid + 256 * k;
        sA[idx >> 7][idx & 127] = attn[(i * 8 + b) * 4096 + idx];
    }
    __syncthreads();
    const int r = tid & 31, dgrp = tid >> 5;
    float acc0 = 0.f, acc1 = 0.f, acc2 = 0.f, acc3 = 0.f;
    #pragma unroll 8
    for (int k = 0; k < 128; ++k) {
        const float a = sA[r][k];
        acc0 = fmaf(a, W_out[k * 32 + dgrp],      acc0);
        acc1 = fmaf(a, W_out[k * 32 + dgrp + 8],  acc1);
        acc2 = fmaf(a, W_out[k * 32 + dgrp + 16], acc2);
        acc3 = fmaf(a, W_out[k * 32 + dgrp + 24], acc3);
    }
    const float dv = expf((float)(2 * (r >> 1)) * C32);
    const float ang = (float)i * dv;
    const float pe = (r & 1) ? cosf(ang) : sinf(ang);
    const int base = i * 32 + r;
    z[(b * 32 + dgrp)      * 512 + base] = acc0 + b_out[dgrp]      + pe;
    z[(b * 32 + dgrp + 8)  * 512 + base] = acc1 + b_out[dgrp + 8]  + pe;
    z[(b * 32 + dgrp + 16) * 512 + base] = acc2 + b_out[dgrp + 16] + pe;
    z[(b * 32 + dgrp + 24) * 512 + base] = acc3 + b_out[dgrp + 24] + pe;
}

// ---------------------------------------------------------------------------
// K3 v8: 1024 threads/sequence, wave-per-token -> 16 waves/CU = 4 waves/SIMD.
// Lane map: j = lane&31 (dim), kh = lane>>5 (k-half).  All phases wave-local
// except attention (2 barriers/layer).  k-sums split across halves + 1 shfl.
__launch_bounds__(1024, 1)
__global__ void k_former(const float* __restrict__ z,
                         const float* __restrict__ f_Wq, const float* __restrict__ f_Wk,
                         const float* __restrict__ f_Wv, const float* __restrict__ f_Wo,
                         const float* __restrict__ f_bq, const float* __restrict__ f_bk,
                         const float* __restrict__ f_bv, const float* __restrict__ f_bo,
                         const float* __restrict__ f_ln1_g, const float* __restrict__ f_ln1_b,
                         const float* __restrict__ f_W1, const float* __restrict__ f_b1,
                         const float* __restrict__ f_W2, const float* __restrict__ f_b2,
                         const float* __restrict__ f_ln2_g, const float* __restrict__ f_ln2_b,
                         const float* __restrict__ ln_f_g, const float* __restrict__ ln_f_b,
                         const float* __restrict__ W_lin, const float* __restrict__ b_lin,
                         float* __restrict__ out) {
    __shared__ float sZ[16][36];
    __shared__ float sKm[16][36], sVm[16][36], sOm[16][36];
    __shared__ float sH[16][132];
    __shared__ float sZf[512];
    __shared__ float sPart[8][96];
    const int tid = threadIdx.x;
    const int n = blockIdx.x;
    const int s = tid >> 6;          // wave = token
    const int lane = tid & 63;
    const int j = lane & 31;
    const int kh = lane >> 5;        // k-half

    // prologue (wave-local): residual in regs (both halves), row copy in LDS
    float zres = z[n * 512 + s * 32 + j];
    if (kh == 0) sZ[s][j] = zres;

    for (int l = 0; l < 3; ++l) {
        float q_reg;
        // ===== A: QKV, k-sum split across halves =====
        {
            float zr[16];
            #pragma unroll
            for (int k4 = 0; k4 < 4; ++k4) {
                const float4 zv = *(const float4*)&sZ[s][kh * 16 + 4 * k4];
                zr[4 * k4] = zv.x; zr[4 * k4 + 1] = zv.y; zr[4 * k4 + 2] = zv.z; zr[4 * k4 + 3] = zv.w;
            }
            #pragma unroll
            for (int m = 0; m < 3; ++m) {
                const float* Wm = ((m == 0) ? f_Wq : (m == 1) ? f_Wk : f_Wv) + l * 1024;
                float w[16];
                #pragma unroll
                for (int k = 0; k < 16; ++k) w[k] = Wm[(kh * 16 + k) * 32 + j];
                float acc = 0.f;
                #pragma unroll
                for (int k = 0; k < 16; ++k) acc = fmaf(zr[k], w[k], acc);
                acc += __shfl_xor(acc, 32);
                acc += ((m == 0) ? f_bq : (m == 1) ? f_bk : f_bv)[l * 32 + j];
                if (m == 0) q_reg = acc;
                else if (m == 1) { if (kh == 0) sKm[s][j] = acc; }
                else             { if (kh == 0) sVm[s][j] = acc; }
            }
        }
        __syncthreads();   // b1: all tokens' K/V visible
        // ===== B: attention for own token q=s (8 heads x 8 lanes) =====
        {
            const int hh = lane >> 3;      // head
            const int kp = lane & 7;       // covers k-tokens 2kp, 2kp+1
            const int h4 = hh * 4;
            const float qx = __shfl(q_reg, h4);
            const float qy = __shfl(q_reg, h4 + 1);
            const float qz = __shfl(q_reg, h4 + 2);
            const float qw = __shfl(q_reg, h4 + 3);
            const float4 kv0 = *(const float4*)&sKm[2 * kp][h4];
            const float4 kv1 = *(const float4*)&sKm[2 * kp + 1][h4];
            float s0 = (qx * kv0.x + qy * kv0.y + qz * kv0.z + qw * kv0.w) * 0.5f;
            float s1 = (qx * kv1.x + qy * kv1.y + qz * kv1.z + qw * kv1.w) * 0.5f;
            float mx = fmaxf(s0, s1);
            #pragma unroll
            for (int off = 4; off > 0; off >>= 1) mx = fmaxf(mx, __shfl_xor(mx, off));
            const float e0 = __expf(s0 - mx), e1 = __expf(s1 - mx);
            float sum = e0 + e1;
            #pragma unroll
            for (int off = 4; off > 0; off >>= 1) sum += __shfl_xor(sum, off);
            const float4 vv0 = *(const float4*)&sVm[2 * kp][h4];
            const float4 vv1 = *(const float4*)&sVm[2 * kp + 1][h4];
            float o0 = e0 * vv0.x + e1 * vv1.x;
            float o1 = e0 * vv0.y + e1 * vv1.y;
            float o2 = e0 * vv0.z + e1 * vv1.z;
            float o3 = e0 * vv0.w + e1 * vv1.w;
            #pragma unroll
            for (int off = 4; off > 0; off >>= 1) {
                o0 += __shfl_xor(o0, off); o1 += __shfl_xor(o1, off);
                o2 += __shfl_xor(o2, off); o3 += __shfl_xor(o3, off);
            }
            if (kp == 0) {
                const float inv = 1.0f / sum;
                *(float4*)&sOm[s][h4] = make_float4(o0 * inv, o1 * inv, o2 * inv, o3 * inv);
            }
        }
        // (no barrier: sOm row is wave-local)
        // ===== C: O-proj + residual + LN1 (wave-local, k-split) =====
        {
            float w[16], orv[16];
            #pragma unroll
            for (int k = 0; k < 16; ++k) w[k] = f_Wo[l * 1024 + (kh * 16 + k) * 32 + j];
            #pragma unroll
            for (int k4 = 0; k4 < 4; ++k4) {
                const float4 ov = *(const float4*)&sOm[s][kh * 16 + 4 * k4];
                orv[4 * k4] = ov.x; orv[4 * k4 + 1] = ov.y; orv[4 * k4 + 2] = ov.z; orv[4 * k4 + 3] = ov.w;
            }
            float acc = 0.f;
            #pragma unroll
            for (int k = 0; k < 16; ++k) acc = fmaf(orv[k], w[k], acc);
            acc += __shfl_xor(acc, 32);
            const float t = zres + acc + f_bo[l * 32 + j];
            float sm = t, sq = t * t;
            #pragma unroll
            for (int off = 16; off > 0; off >>= 1) { sm += __shfl_xor(sm, off); sq += __shfl_xor(sq, off); }
            const float mu = sm * (1.0f / 32.0f);
            const float rs = rsqrtf(sq * (1.0f / 32.0f) - mu * mu + 1e-5f);
            zres = (t - mu) * rs * f_ln1_g[l * 32 + j] + f_ln1_b[l * 32 + j];
            if (kh == 0) sZ[s][j] = zres;
        }
        // ===== D: FFN1 + gelu (wave-local; lane owns f=lane, lane+64) =====
        {
            const int f0 = lane, f1 = lane + 64;
            float wa[32], wb[32];
            #pragma unroll
            for (int k = 0; k < 32; ++k) {
                wa[k] = f_W1[l * 4096 + k * 128 + f0];
                wb[k] = f_W1[l * 4096 + k * 128 + f1];
            }
            float a0 = f_b1[l * 128 + f0], a1 = f_b1[l * 128 + f1];
            #pragma unroll
            for (int k4 = 0; k4 < 8; ++k4) {
                const float4 zv = *(const float4*)&sZ[s][4 * k4];
                a0 = fmaf(zv.x, wa[4 * k4], a0);     a0 = fmaf(zv.y, wa[4 * k4 + 1], a0);
                a0 = fmaf(zv.z, wa[4 * k4 + 2], a0); a0 = fmaf(zv.w, wa[4 * k4 + 3], a0);
                a1 = fmaf(zv.x, wb[4 * k4], a1);     a1 = fmaf(zv.y, wb[4 * k4 + 1], a1);
                a1 = fmaf(zv.z, wb[4 * k4 + 2], a1); a1 = fmaf(zv.w, wb[4 * k4 + 3], a1);
            }
            const float ea = __expf(1.5957691216057308f * (a0 + 0.044715f * a0 * a0 * a0));
            const float eb = __expf(1.5957691216057308f * (a1 + 0.044715f * a1 * a1 * a1));
            sH[s][f0] = 0.5f * a0 * (2.0f - 2.0f / (ea + 1.0f));
            sH[s][f1] = 0.5f * a1 * (2.0f - 2.0f / (eb + 1.0f));
        }
        // ===== E: FFN2 + residual + LN2 (wave-local; 64-deep k-half) =====
        {
            float acc = 0.f;
            #pragma unroll
            for (int kc = 0; kc < 2; ++kc) {
                float w[32];
                #pragma unroll
                for (int k = 0; k < 32; ++k) w[k] = f_W2[l * 4096 + (kh * 64 + kc * 32 + k) * 32 + j];
                #pragma unroll
                for (int k4 = 0; k4 < 8; ++k4) {
                    const float4 hv = *(const float4*)&sH[s][kh * 64 + kc * 32 + 4 * k4];
                    acc = fmaf(hv.x, w[4 * k4], acc);     acc = fmaf(hv.y, w[4 * k4 + 1], acc);
                    acc = fmaf(hv.z, w[4 * k4 + 2], acc); acc = fmaf(hv.w, w[4 * k4 + 3], acc);
                }
            }
            acc += __shfl_xor(acc, 32);
            const float t = zres + acc + f_b2[l * 32 + j];
            float sm = t, sq = t * t;
            #pragma unroll
            for (int off = 16; off > 0; off >>= 1) { sm += __shfl_xor(sm, off); sq += __shfl_xor(sq, off); }
            const float mu = sm * (1.0f / 32.0f);
            const float rs = rsqrtf(sq * (1.0f / 32.0f) - mu * mu + 1e-5f);
            zres = (t - mu) * rs * f_ln2_g[l * 32 + j] + f_ln2_b[l * 32 + j];
            if (kh == 0) sZ[s][j] = zres;
        }
        __syncthreads();   // b2: attention reads of this layer done; K/V reusable
    }
    // ===== final LN (wave-local) + transposed zf write =====
    {
        const float t = zres;
        float sm = t, sq = t * t;
        #pragma unroll
        for (int off = 16; off > 0; off >>= 1) { sm += __shfl_xor(sm, off); sq += __shfl_xor(sq, off); }
        const float mu = sm * (1.0f / 32.0f);
        const float rs = rsqrtf(sq * (1.0f / 32.0f) - mu * mu + 1e-5f);
        if (kh == 0) sZf[j * 16 + s] = (t - mu) * rs * ln_f_g[j] + ln_f_b[j];
    }
    __syncthreads();   // b-head1
    // ===== head: 8-way k-split x 96 outputs =====
    if (tid < 768) {
        const int c = tid / 96, o = tid % 96;
        const int j0 = c * 64;
        float acc = 0.f;
        #pragma unroll 16
        for (int jj = 0; jj < 64; ++jj)
            acc = fmaf(sZf[j0 + jj], W_lin[(j0 + jj) * 96 + o], acc);
        sPart[c][o] = acc;
    }
    __syncthreads();   // b-head2
    if (tid < 96) {
        float acc = b_lin[tid];
        #pragma unroll
        for (int c = 0; c < 8; ++c) acc += sPart[c][tid];
        out[((n >> 5) * 96 + tid) * 32 + (n & 31)] = acc;
    }
}

// ---------------------------------------------------------------------------
extern "C" void kernel_launch(void* const* d_in, const int* in_sizes, int n_in,
                              void* d_out, int out_size, void* d_ws, size_t ws_size,
                              hipStream_t stream) {
    const float* x       = (const float*)d_in[0];
    const float* x_mark  = (const float*)d_in[1];
    const float* x_mask  = (const float*)d_in[2];
    const float* Wq      = (const float*)d_in[3];
    const float* Wk      = (const float*)d_in[4];
    const float* W_out   = (const float*)d_in[5];
    const float* b_out   = (const float*)d_in[6];
    const float* f_Wq    = (const float*)d_in[7];
    const float* f_Wk    = (const float*)d_in[8];
    const float* f_Wv    = (const float*)d_in[9];
    const float* f_Wo    = (const float*)d_in[10];
    const float* f_bq    = (const float*)d_in[11];
    const float* f_bk    = (const float*)d_in[12];
    const float* f_bv    = (const float*)d_in[13];
    const float* f_bo    = (const float*)d_in[14];
    const float* f_ln1_g = (const float*)d_in[15];
    const float* f_ln1_b = (const float*)d_in[16];
    const float* f_W1    = (const float*)d_in[17];
    const float* f_b1    = (const float*)d_in[18];
    const float* f_W2    = (const float*)d_in[19];
    const float* f_b2    = (const float*)d_in[20];
    const float* f_ln2_g = (const float*)d_in[21];
    const float* f_ln2_b = (const float*)d_in[22];
    const float* ln_f_g  = (const float*)d_in[23];
    const float* ln_f_b  = (const float*)d_in[24];
    const float* W_lin   = (const float*)d_in[25];
    const float* b_lin   = (const float*)d_in[26];

    float* ws = (float*)d_ws;
    float* Kmat      = ws;                      // 4096*128 = 524288
    float* Qall      = ws + 524288;             // 512*128  = 65536
    unsigned* obsB   = (unsigned*)(ws + 589824);// 4096 words
    float* attn      = ws + 593920;             // 16*8*32*128 = 524288
    float* zbuf      = ws + 1118208;            // 256*16*32 = 131072   (total ~5.0 MB)

    k_embed_mm<<<656, 256, 0, stream>>>(x_mark, Wk, Wq, x_mask, Kmat, Qall, obsB);
    k_patch_attn<<<512, 256, 0, stream>>>(x, x_mark, obsB, Kmat, Qall, attn);
    k_reprs<<<128, 256, 0, stream>>>(attn, W_out, b_out, zbuf);
    k_former<<<256, 1024, 0, stream>>>(zbuf,
        f_Wq, f_Wk, f_Wv, f_Wo, f_bq, f_bk, f_bv, f_bo,
        f_ln1_g, f_ln1_b, f_W1, f_b1, f_W2, f_b2, f_ln2_g, f_ln2_b,
        ln_f_g, ln_f_b, W_lin, b_lin, (float*)d_out);
}

// Round 11
// 63.992 us; speedup vs baseline: 1.0572x; 1.0572x over previous
//
#include <hip/hip_runtime.h>
#include <math.h>

// Model_78271484002488: B=8, L=512, D=32, N_PATCHES=16, N_REF=32, LAT=128, HM=4,
// FH=8, NL=3, FF=128, PRED=96.  All f32.

#define ISQ32 0.17677669529663687f   // 1/sqrt(32)
#define C128  (-0.07195578415606394f)  // -ln(1e4)/128
#define C32   (-0.28782313662425575f)  // -ln(1e4)/32

// ---------------------------------------------------------------------------
// K0: blocks [0,144): embed matvec, 32 rows/block (8 rows/wave).
//     blocks [144,656): obsBits via ballot.
__launch_bounds__(256)
__global__ void k_embed_mm(const float* __restrict__ x_mark,
                           const float* __restrict__ Wk,
                           const float* __restrict__ Wq,
                           const float* __restrict__ x_mask,
                           float* __restrict__ Kmat,
                           float* __restrict__ Qall,
                           unsigned* __restrict__ obsBits) {
    if (blockIdx.x >= 144) {
        const int gt = (blockIdx.x - 144) * 256 + threadIdx.x;
        const int w = gt >> 6, lane = gt & 63;
        const int bl = w * 2 + (lane >> 5);
        const int d = lane & 31;
        const unsigned long long mm = __ballot(x_mask[bl * 32 + d] > 0.0f);
        if (lane == 0)  obsBits[w * 2]     = (unsigned)(mm & 0xffffffffull);
        if (lane == 32) obsBits[w * 2 + 1] = (unsigned)(mm >> 32);
        return;
    }
    __shared__ float sTe[32][128];
    const int wv = threadIdx.x >> 6;
    const int lane = threadIdx.x & 63;
    const int bb = blockIdx.x;
    const int row0 = bb * 32 + wv * 8;
    const float dv = __expf((float)(2 * lane) * C128);
    #pragma unroll
    for (int rr = 0; rr < 8; ++rr) {
        const int row = row0 + rr;
        const float t = (row < 4096) ? x_mark[row] : (float)(row - 4096) * (512.0f / 511.0f);
        const float ang = t * dv;
        sTe[wv * 8 + rr][2 * lane]     = __sinf(ang);
        sTe[wv * 8 + rr][2 * lane + 1] = __cosf(ang);
    }
    __syncthreads();
    const float* W = (bb < 128) ? Wk : Wq;
    float a0[8], a1[8];
    #pragma unroll
    for (int rr = 0; rr < 8; ++rr) { a0[rr] = 0.f; a1[rr] = 0.f; }
    for (int k = 0; k < 128; ++k) {
        const float wa = W[k * 128 + lane];
        const float wb = W[k * 128 + lane + 64];
        #pragma unroll
        for (int rr = 0; rr < 8; ++rr) {
            const float te = sTe[wv * 8 + rr][k];
            a0[rr] = fmaf(te, wa, a0[rr]);
            a1[rr] = fmaf(te, wb, a1[rr]);
        }
    }
    #pragma unroll
    for (int rr = 0; rr < 8; ++rr) {
        const int row = row0 + rr;
        float* outp = (row < 4096) ? (Kmat + row * 128) : (Qall + (row - 4096) * 128);
        outp[lane] = a0[rr];
        outp[lane + 64] = a1[rr];
    }
}

// ---------------------------------------------------------------------------
// K1: fused patch attention, range-based.  block = (i,b,h); 256 threads.
__launch_bounds__(256)
__global__ void k_patch_attn(const float* __restrict__ x,
                             const float* __restrict__ x_mark,
                             const unsigned* __restrict__ obsBits,
                             const float* __restrict__ Kmat,
                             const float* __restrict__ Qall,
                             float* __restrict__ attn) {
    __shared__ float sQ[32][36];
    __shared__ float sK[96][36];
    __shared__ float sX[96][36];
    __shared__ float sS[32][100];
    __shared__ unsigned sBits[96];
    __shared__ int sLo, sHi;
    __shared__ unsigned sAV;
    const int tid = threadIdx.x;
    const int h = blockIdx.x & 3;
    const int b = (blockIdx.x >> 2) & 7;
    const int i = blockIdx.x >> 5;
    const float e0 = 32.0f * (float)i, e1 = 32.0f * (float)(i + 1);
    if (tid == 0) { sLo = 512; sHi = -1; sAV = 0u; }
    __syncthreads();
    #pragma unroll
    for (int k = 0; k < 4; ++k) {
        const int idx = tid + 256 * k;
        sQ[idx >> 5][idx & 31] = Qall[(i * 32 + (idx >> 5)) * 128 + h * 32 + (idx & 31)];
    }
    {
        int mylo = 512, myhi = -1;
        unsigned mybits = 0u;
        #pragma unroll
        for (int k = 0; k < 2; ++k) {
            const int l = tid + 256 * k;
            const float t = x_mark[b * 512 + l];
            if (t >= e0 && t <= e1) {
                mylo = min(mylo, l);
                myhi = max(myhi, l);
                mybits |= obsBits[b * 512 + l];
            }
        }
        #pragma unroll
        for (int off = 32; off > 0; off >>= 1) {
            mylo = min(mylo, __shfl_xor(mylo, off));
            myhi = max(myhi, __shfl_xor(myhi, off));
            mybits |= __shfl_xor(mybits, off);
        }
        if ((tid & 63) == 0) {
            atomicMin(&sLo, mylo);
            atomicMax(&sHi, myhi);
            atomicOr(&sAV, mybits);
        }
    }
    __syncthreads();
    const int lo = sLo, hi = sHi;
    const int NA = hi - lo + 1;
    const unsigned av = sAV;
    const int r = tid >> 3, dg = tid & 7;

    if (NA >= 1 && NA <= 96 && av == 0xffffffffu) {
        if (tid < NA) sBits[tid] = obsBits[b * 512 + lo + tid];
        for (int idx = tid; idx < NA * 32; idx += 256) {
            const int ll = idx >> 5, c = idx & 31;
            sK[ll][c] = Kmat[(b * 512 + lo + ll) * 128 + h * 32 + c];
            sX[ll][c] = x[(b * 512 + lo + ll) * 32 + c];
        }
        __syncthreads();
        float m = -1e30f;
        for (int ll = dg; ll < NA; ll += 8) {
            float p0 = 0.f, p1 = 0.f, p2 = 0.f, p3 = 0.f;
            #pragma unroll
            for (int e = 0; e < 32; e += 4) {
                p0 = fmaf(sQ[r][e],     sK[ll][e],     p0);
                p1 = fmaf(sQ[r][e + 1], sK[ll][e + 1], p1);
                p2 = fmaf(sQ[r][e + 2], sK[ll][e + 2], p2);
                p3 = fmaf(sQ[r][e + 3], sK[ll][e + 3], p3);
            }
            const float s = (p0 + p1 + p2 + p3) * ISQ32;
            sS[r][ll] = s;
            m = fmaxf(m, s);
        }
        #pragma unroll
        for (int off = 4; off > 0; off >>= 1) m = fmaxf(m, __shfl_xor(m, off));
        for (int ll = dg; ll < NA; ll += 8) sS[r][ll] = __expf(sS[r][ll] - m);
        __syncthreads();
        float num0 = 0.f, num1 = 0.f, num2 = 0.f, num3 = 0.f;
        float den0 = 0.f, den1 = 0.f, den2 = 0.f, den3 = 0.f;
        for (int ll = 0; ll < NA; ++ll) {
            const float e = sS[r][ll];
            const unsigned bits = sBits[ll];
            if ((bits >> dg) & 1u)        { den0 += e; num0 = fmaf(e, sX[ll][dg],      num0); }
            if ((bits >> (dg + 8)) & 1u)  { den1 += e; num1 = fmaf(e, sX[ll][dg + 8],  num1); }
            if ((bits >> (dg + 16)) & 1u) { den2 += e; num2 = fmaf(e, sX[ll][dg + 16], num2); }
            if ((bits >> (dg + 24)) & 1u) { den3 += e; num3 = fmaf(e, sX[ll][dg + 24], num3); }
        }
        float* ap = attn + ((i * 8 + b) * 32 + r) * 128 + h * 32;
        ap[dg]      = num0 / den0;
        ap[dg + 8]  = num1 / den1;
        ap[dg + 16] = num2 / den2;
        ap[dg + 24] = num3 / den3;
    } else {
        float m = -1e30f;
        float num[4] = {0.f, 0.f, 0.f, 0.f}, den[4] = {0.f, 0.f, 0.f, 0.f};
        for (int l = 0; l < 512; ++l) {
            const float t = x_mark[b * 512 + l];
            const unsigned bits = obsBits[b * 512 + l];
            const bool inr = (t >= e0 && t <= e1);
            const unsigned effD = (inr ? bits : 0u) | ~av;
            if (effD == 0u) continue;
            const unsigned effN = effD & bits;
            const float* Kp = Kmat + (b * 512 + l) * 128 + h * 32;
            float a = 0.f;
            #pragma unroll
            for (int e2 = 0; e2 < 32; ++e2) a = fmaf(sQ[r][e2], Kp[e2], a);
            const float s = a * ISQ32;
            float eNew;
            if (s > m) {
                const float scale = __expf(m - s);
                #pragma unroll
                for (int jj = 0; jj < 4; ++jj) { den[jj] *= scale; num[jj] *= scale; }
                m = s;
                eNew = 1.0f;
            } else {
                eNew = __expf(s - m);
            }
            const float* xp = x + (b * 512 + l) * 32;
            #pragma unroll
            for (int jj = 0; jj < 4; ++jj) {
                const int d = dg + 8 * jj;
                if ((effD >> d) & 1u) den[jj] += eNew;
                if ((effN >> d) & 1u) num[jj] = fmaf(eNew, xp[d], num[jj]);
            }
        }
        float* ap = attn + ((i * 8 + b) * 32 + r) * 128 + h * 32;
        #pragma unroll
        for (int jj = 0; jj < 4; ++jj) ap[dg + 8 * jj] = num[jj] / den[jj];
    }
}

// ---------------------------------------------------------------------------
// K2: reprs = attn(B,32,128) @ W_out + b_out;  z[(b*32+d)][i][r] = reprs + te16(i,r)
__global__ void k_reprs(const float* __restrict__ attn,
                        const float* __restrict__ W_out,
                        const float* __restrict__ b_out,
                        float* __restrict__ z) {
    __shared__ float sA[32][129];
    const int tid = threadIdx.x;
    const int b = blockIdx.x & 7;
    const int i = blockIdx.x >> 3;
    #pragma unroll
    for (int k = 0; k < 16; ++k) {
        const int idx = tid + 256 * k;
        sA[idx >> 7][idx & 127] = attn[(i * 8 + b) * 4096 + idx];
    }
    __syncthreads();
    const int r = tid & 31, dgrp = tid >> 5;
    float acc0 = 0.f, acc1 = 0.f, acc2 = 0.f, acc3 = 0.f;
    #pragma unroll 8
    for (int k = 0; k < 128; ++k) {
        const float a = sA[r][k];
        acc0 = fmaf(a, W_out[k * 32 + dgrp],      acc0);
        acc1 = fmaf(a, W_out[k * 32 + dgrp + 8],  acc1);
        acc2 = fmaf(a, W_out[k * 32 + dgrp + 16], acc2);
        acc3 = fmaf(a, W_out[k * 32 + dgrp + 24], acc3);
    }
    const float dv = expf((float)(2 * (r >> 1)) * C32);
    const float ang = (float)i * dv;
    const float pe = (r & 1) ? cosf(ang) : sinf(ang);
    const int base = i * 32 + r;
    z[(b * 32 + dgrp)      * 512 + base] = acc0 + b_out[dgrp]      + pe;
    z[(b * 32 + dgrp + 8)  * 512 + base] = acc1 + b_out[dgrp + 8]  + pe;
    z[(b * 32 + dgrp + 16) * 512 + base] = acc2 + b_out[dgrp + 16] + pe;
    z[(b * 32 + dgrp + 24) * 512 + base] = acc3 + b_out[dgrp + 24] + pe;
}

// ---------------------------------------------------------------------------
// K3 v9: v7's wave-local structure + ALL weights staged per layer into LDS in
// TRANSPOSED padded layouts, so every phase reads weight columns as (<=2-way,
// i.e. free) ds_read_b128 at LDS latency instead of global/L2 latency.
// Wave wv owns tokens 4wv..4wv+3; lane: j=lane&31, half2=lane>>5 -> tokens
// sA,sB.  Barriers: 3/layer (post-staging, pre-attn, end-of-layer) + 2 head.
__launch_bounds__(256, 1)
__global__ void k_former(const float* __restrict__ z,
                         const float* __restrict__ f_Wq, const float* __restrict__ f_Wk,
                         const float* __restrict__ f_Wv, const float* __restrict__ f_Wo,
                         const float* __restrict__ f_bq, const float* __restrict__ f_bk,
                         const float* __restrict__ f_bv, const float* __restrict__ f_bo,
                         const float* __restrict__ f_ln1_g, const float* __restrict__ f_ln1_b,
                         const float* __restrict__ f_W1, const float* __restrict__ f_b1,
                         const float* __restrict__ f_W2, const float* __restrict__ f_b2,
                         const float* __restrict__ f_ln2_g, const float* __restrict__ f_ln2_b,
                         const float* __restrict__ ln_f_g, const float* __restrict__ ln_f_b,
                         const float* __restrict__ W_lin, const float* __restrict__ b_lin,
                         float* __restrict__ out) {
    __shared__ float wT[4][32][36];   // Wq^T,Wk^T,Wv^T,Wo^T: wT[m][j][k]
    __shared__ float w1T[128][36];    // W1^T: w1T[f][k]
    __shared__ float w2T[32][140];    // W2^T: w2T[j][k], pad 140 -> 2-way max
    __shared__ float sZ[16][36];
    __shared__ float sQm[16][36], sKm[16][36], sVm[16][36], sOm[16][36];
    __shared__ float sH[16][132];
    __shared__ float sZf[512];
    __shared__ float sPart[2][96];
    const int tid = threadIdx.x;
    const int n = blockIdx.x;
    const int wv = tid >> 6;
    const int lane = tid & 63;
    const int j = lane & 31, half2 = lane >> 5;
    const int sA = wv * 4 + half2 * 2, sB = sA + 1;
    const int m4 = tid >> 6, t64 = tid & 63;    // staging roles

    // prologue (wave-local writes; ordered before QKV by b0)
    float zresA = z[n * 512 + sA * 32 + j];
    float zresB = z[n * 512 + sB * 32 + j];
    sZ[sA][j] = zresA;
    sZ[sB][j] = zresB;

    for (int l = 0; l < 3; ++l) {
        // ---- stage layer l weights, transposed ----
        {
            const float* Wm4 = ((m4 == 0) ? f_Wq : (m4 == 1) ? f_Wk : (m4 == 2) ? f_Wv : f_Wo) + l * 1024;
            #pragma unroll
            for (int r = 0; r < 4; ++r) {
                const int idx4 = r * 64 + t64;
                const float4 v = ((const float4*)Wm4)[idx4];
                const int k = idx4 >> 3, j0 = (idx4 & 7) << 2;
                wT[m4][j0 + 0][k] = v.x;
                wT[m4][j0 + 1][k] = v.y;
                wT[m4][j0 + 2][k] = v.z;
                wT[m4][j0 + 3][k] = v.w;
            }
            #pragma unroll
            for (int r = 0; r < 4; ++r) {
                const int idx4 = r * 256 + tid;
                const float4 v = ((const float4*)(f_W1 + l * 4096))[idx4];
                const int k = idx4 >> 5, f0 = (idx4 & 31) << 2;
                w1T[f0 + 0][k] = v.x;
                w1T[f0 + 1][k] = v.y;
                w1T[f0 + 2][k] = v.z;
                w1T[f0 + 3][k] = v.w;
            }
            #pragma unroll
            for (int r = 0; r < 4; ++r) {
                const int idx4 = r * 256 + tid;
                const float4 v = ((const float4*)(f_W2 + l * 4096))[idx4];
                const int k = idx4 >> 3, j0 = (idx4 & 7) << 2;
                w2T[j0 + 0][k] = v.x;
                w2T[j0 + 1][k] = v.y;
                w2T[j0 + 2][k] = v.z;
                w2T[j0 + 3][k] = v.w;
            }
        }
        __syncthreads();   // b0: weights staged
        // ===== A: QKV for own 2 tokens (wave-local; weights from LDS) =====
        {
            float4 zra[8], zrb[8];
            #pragma unroll
            for (int k4 = 0; k4 < 8; ++k4) {
                zra[k4] = *(const float4*)&sZ[sA][4 * k4];
                zrb[k4] = *(const float4*)&sZ[sB][4 * k4];
            }
            #pragma unroll
            for (int m = 0; m < 3; ++m) {
                float aA = 0.f, aB = 0.f;
                #pragma unroll
                for (int k4 = 0; k4 < 8; ++k4) {
                    const float4 w = *(const float4*)&wT[m][j][4 * k4];
                    aA = fmaf(zra[k4].x, w.x, aA); aA = fmaf(zra[k4].y, w.y, aA);
                    aA = fmaf(zra[k4].z, w.z, aA); aA = fmaf(zra[k4].w, w.w, aA);
                    aB = fmaf(zrb[k4].x, w.x, aB); aB = fmaf(zrb[k4].y, w.y, aB);
                    aB = fmaf(zrb[k4].z, w.z, aB); aB = fmaf(zrb[k4].w, w.w, aB);
                }
                const float bias = ((m == 0) ? f_bq : (m == 1) ? f_bk : f_bv)[l * 32 + j];
                float (*dst)[36] = (m == 0) ? sQm : (m == 1) ? sKm : sVm;
                dst[sA][j] = aA + bias;
                dst[sB][j] = aB + bias;
            }
        }
        __syncthreads();   // b1: all waves' Q/K/V visible
        // ===== B: attention for own 4 q-tokens (reads all K/V) =====
        {
            const int ql = (lane >> 3) & 3, hh = lane & 7, kh = lane >> 5;
            const int q = wv * 4 + ql, h4 = hh * 4;
            const float4 qv = *(const float4*)&sQm[q][h4];
            float sc[8];
            float mx = -1e30f;
            #pragma unroll
            for (int m = 0; m < 8; ++m) {
                const float4 kv = *(const float4*)&sKm[kh * 8 + m][h4];
                sc[m] = (qv.x * kv.x + qv.y * kv.y + qv.z * kv.z + qv.w * kv.w) * 0.5f;
                mx = fmaxf(mx, sc[m]);
            }
            mx = fmaxf(mx, __shfl_xor(mx, 32));
            float sum = 0.f;
            #pragma unroll
            for (int m = 0; m < 8; ++m) { sc[m] = __expf(sc[m] - mx); sum += sc[m]; }
            sum += __shfl_xor(sum, 32);
            float o0 = 0.f, o1 = 0.f, o2 = 0.f, o3 = 0.f;
            #pragma unroll
            for (int m = 0; m < 8; ++m) {
                const float4 vv = *(const float4*)&sVm[kh * 8 + m][h4];
                o0 = fmaf(sc[m], vv.x, o0); o1 = fmaf(sc[m], vv.y, o1);
                o2 = fmaf(sc[m], vv.z, o2); o3 = fmaf(sc[m], vv.w, o3);
            }
            o0 += __shfl_xor(o0, 32); o1 += __shfl_xor(o1, 32);
            o2 += __shfl_xor(o2, 32); o3 += __shfl_xor(o3, 32);
            if (kh == 0) {
                const float inv = 1.0f / sum;
                *(float4*)&sOm[q][h4] = make_float4(o0 * inv, o1 * inv, o2 * inv, o3 * inv);
            }
        }
        // (no barrier: sOm rows are wave-local)
        // ===== C: O-proj + residual + LN1 (wave-local) =====
        {
            float oa = 0.f, ob = 0.f;
            #pragma unroll
            for (int k4 = 0; k4 < 8; ++k4) {
                const float4 w  = *(const float4*)&wT[3][j][4 * k4];
                const float4 va = *(const float4*)&sOm[sA][4 * k4];
                const float4 vb = *(const float4*)&sOm[sB][4 * k4];
                oa = fmaf(va.x, w.x, oa); oa = fmaf(va.y, w.y, oa);
                oa = fmaf(va.z, w.z, oa); oa = fmaf(va.w, w.w, oa);
                ob = fmaf(vb.x, w.x, ob); ob = fmaf(vb.y, w.y, ob);
                ob = fmaf(vb.z, w.z, ob); ob = fmaf(vb.w, w.w, ob);
            }
            const float bo = f_bo[l * 32 + j];
            const float t0 = zresA + oa + bo;
            const float t1 = zresB + ob + bo;
            float s0 = t0, q0 = t0 * t0, s1 = t1, q1 = t1 * t1;
            #pragma unroll
            for (int off = 16; off > 0; off >>= 1) {
                s0 += __shfl_xor(s0, off); q0 += __shfl_xor(q0, off);
                s1 += __shfl_xor(s1, off); q1 += __shfl_xor(q1, off);
            }
            const float mu0 = s0 * (1.0f / 32.0f);
            const float rs0 = rsqrtf(q0 * (1.0f / 32.0f) - mu0 * mu0 + 1e-5f);
            const float mu1 = s1 * (1.0f / 32.0f);
            const float rs1 = rsqrtf(q1 * (1.0f / 32.0f) - mu1 * mu1 + 1e-5f);
            const float g1 = f_ln1_g[l * 32 + j], be1 = f_ln1_b[l * 32 + j];
            zresA = (t0 - mu0) * rs0 * g1 + be1;
            zresB = (t1 - mu1) * rs1 * g1 + be1;
            sZ[sA][j] = zresA;
            sZ[sB][j] = zresB;
        }
        // ===== D: FFN1 + gelu (wave-local; f = j + 32*fm) =====
        {
            float4 zra[8], zrb[8];
            #pragma unroll
            for (int k4 = 0; k4 < 8; ++k4) {
                zra[k4] = *(const float4*)&sZ[sA][4 * k4];
                zrb[k4] = *(const float4*)&sZ[sB][4 * k4];
            }
            #pragma unroll
            for (int fm = 0; fm < 4; ++fm) {
                const int f = j + 32 * fm;
                const float b1v = f_b1[l * 128 + f];
                float aA = b1v, aB = b1v;
                #pragma unroll
                for (int k4 = 0; k4 < 8; ++k4) {
                    const float4 w = *(const float4*)&w1T[f][4 * k4];
                    aA = fmaf(zra[k4].x, w.x, aA); aA = fmaf(zra[k4].y, w.y, aA);
                    aA = fmaf(zra[k4].z, w.z, aA); aA = fmaf(zra[k4].w, w.w, aA);
                    aB = fmaf(zrb[k4].x, w.x, aB); aB = fmaf(zrb[k4].y, w.y, aB);
                    aB = fmaf(zrb[k4].z, w.z, aB); aB = fmaf(zrb[k4].w, w.w, aB);
                }
                const float ea = __expf(1.5957691216057308f * (aA + 0.044715f * aA * aA * aA));
                const float eb = __expf(1.5957691216057308f * (aB + 0.044715f * aB * aB * aB));
                sH[sA][f] = 0.5f * aA * (2.0f - 2.0f / (ea + 1.0f));
                sH[sB][f] = 0.5f * aB * (2.0f - 2.0f / (eb + 1.0f));
            }
        }
        // ===== E: FFN2 + residual + LN2 (wave-local) =====
        {
            float fa = 0.f, fb = 0.f;
            #pragma unroll
            for (int k4 = 0; k4 < 32; ++k4) {
                const float4 w  = *(const float4*)&w2T[j][4 * k4];
                const float4 ha = *(const float4*)&sH[sA][4 * k4];
                const float4 hb = *(const float4*)&sH[sB][4 * k4];
                fa = fmaf(ha.x, w.x, fa); fa = fmaf(ha.y, w.y, fa);
                fa = fmaf(ha.z, w.z, fa); fa = fmaf(ha.w, w.w, fa);
                fb = fmaf(hb.x, w.x, fb); fb = fmaf(hb.y, w.y, fb);
                fb = fmaf(hb.z, w.z, fb); fb = fmaf(hb.w, w.w, fb);
            }
            const float b2v = f_b2[l * 32 + j];
            const float t0 = zresA + fa + b2v;
            const float t1 = zresB + fb + b2v;
            float s0 = t0, q0 = t0 * t0, s1 = t1, q1 = t1 * t1;
            #pragma unroll
            for (int off = 16; off > 0; off >>= 1) {
                s0 += __shfl_xor(s0, off); q0 += __shfl_xor(q0, off);
                s1 += __shfl_xor(s1, off); q1 += __shfl_xor(q1, off);
            }
            const float mu0 = s0 * (1.0f / 32.0f);
            const float rs0 = rsqrtf(q0 * (1.0f / 32.0f) - mu0 * mu0 + 1e-5f);
            const float mu1 = s1 * (1.0f / 32.0f);
            const float rs1 = rsqrtf(q1 * (1.0f / 32.0f) - mu1 * mu1 + 1e-5f);
            const float g2 = f_ln2_g[l * 32 + j], be2 = f_ln2_b[l * 32 + j];
            zresA = (t0 - mu0) * rs0 * g2 + be2;
            zresB = (t1 - mu1) * rs1 * g2 + be2;
            sZ[sA][j] = zresA;
            sZ[sB][j] = zresB;
        }
        __syncthreads();   // b3: all waves done with this layer's weights + attn reads
    }
    // ===== final LN (wave-local) + transposed zf write =====
    {
        const float t0 = zresA, t1 = zresB;
        float s0 = t0, q0 = t0 * t0, s1 = t1, q1 = t1 * t1;
        #pragma unroll
        for (int off = 16; off > 0; off >>= 1) {
            s0 += __shfl_xor(s0, off); q0 += __shfl_xor(q0, off);
            s1 += __shfl_xor(s1, off); q1 += __shfl_xor(q1, off);
        }
        const float mu0 = s0 * (1.0f / 32.0f);
        const float rs0 = rsqrtf(q0 * (1.0f / 32.0f) - mu0 * mu0 + 1e-5f);
        const float mu1 = s1 * (1.0f / 32.0f);
        const float rs1 = rsqrtf(q1 * (1.0f / 32.0f) - mu1 * mu1 + 1e-5f);
        const float gf = ln_f_g[j], bf = ln_f_b[j];
        sZf[j * 16 + sA] = (t0 - mu0) * rs0 * gf + bf;    // zf[r*16+p], r=j, p=s
        sZf[j * 16 + sB] = (t1 - mu1) * rs1 * gf + bf;
    }
    __syncthreads();   // b-head1
    if (tid < 192) {
        const int half = tid / 96, o = tid % 96;
        const int j0 = half * 256;
        float acc = 0.f;
        #pragma unroll 32
        for (int jj = 0; jj < 256; ++jj)
            acc = fmaf(sZf[j0 + jj], W_lin[(j0 + jj) * 96 + o], acc);
        sPart[half][o] = acc;
    }
    __syncthreads();   // b-head2
    if (tid < 96)
        out[((n >> 5) * 96 + tid) * 32 + (n & 31)] = sPart[0][tid] + sPart[1][tid] + b_lin[tid];
}

// ---------------------------------------------------------------------------
extern "C" void kernel_launch(void* const* d_in, const int* in_sizes, int n_in,
                              void* d_out, int out_size, void* d_ws, size_t ws_size,
                              hipStream_t stream) {
    const float* x       = (const float*)d_in[0];
    const float* x_mark  = (const float*)d_in[1];
    const float* x_mask  = (const float*)d_in[2];
    const float* Wq      = (const float*)d_in[3];
    const float* Wk      = (const float*)d_in[4];
    const float* W_out   = (const float*)d_in[5];
    const float* b_out   = (const float*)d_in[6];
    const float* f_Wq    = (const float*)d_in[7];
    const float* f_Wk    = (const float*)d_in[8];
    const float* f_Wv    = (const float*)d_in[9];
    const float* f_Wo    = (const float*)d_in[10];
    const float* f_bq    = (const float*)d_in[11];
    const float* f_bk    = (const float*)d_in[12];
    const float* f_bv    = (const float*)d_in[13];
    const float* f_bo    = (const float*)d_in[14];
    const float* f_ln1_g = (const float*)d_in[15];
    const float* f_ln1_b = (const float*)d_in[16];
    const float* f_W1    = (const float*)d_in[17];
    const float* f_b1    = (const float*)d_in[18];
    const float* f_W2    = (const float*)d_in[19];
    const float* f_b2    = (const float*)d_in[20];
    const float* f_ln2_g = (const float*)d_in[21];
    const float* f_ln2_b = (const float*)d_in[22];
    const float* ln_f_g  = (const float*)d_in[23];
    const float* ln_f_b  = (const float*)d_in[24];
    const float* W_lin   = (const float*)d_in[25];
    const float* b_lin   = (const float*)d_in[26];

    float* ws = (float*)d_ws;
    float* Kmat      = ws;                      // 4096*128 = 524288
    float* Qall      = ws + 524288;             // 512*128  = 65536
    unsigned* obsB   = (unsigned*)(ws + 589824);// 4096 words
    float* attn      = ws + 593920;             // 16*8*32*128 = 524288
    float* zbuf      = ws + 1118208;            // 256*16*32 = 131072   (total ~5.0 MB)

    k_embed_mm<<<656, 256, 0, stream>>>(x_mark, Wk, Wq, x_mask, Kmat, Qall, obsB);
    k_patch_attn<<<512, 256, 0, stream>>>(x, x_mark, obsB, Kmat, Qall, attn);
    k_reprs<<<128, 256, 0, stream>>>(attn, W_out, b_out, zbuf);
    k_former<<<256, 256, 0, stream>>>(zbuf,
        f_Wq, f_Wk, f_Wv, f_Wo, f_bq, f_bk, f_bv, f_bo,
        f_ln1_g, f_ln1_b, f_W1, f_b1, f_W2, f_b2, f_ln2_g, f_ln2_b,
        ln_f_g, ln_f_b, W_lin, b_lin, (float*)d_out);
}